// Round 11
// baseline (137.201 us; speedup 1.0000x reference)
//
#include <hip/hip_runtime.h>
#include <hip/hip_bf16.h>

// DTLN single-step inference, ONE kernel, ZERO grid barriers (tagged
// dataflow, mechanism proven round 10: (epoch<<32)|f32 words through the
// MALL via relaxed agent-scope atomics; one round-trip per hop).
//
// Round-11 critical-path cuts:
//  1. LSTM gate activations computed in PARALLEL by each wave's lane0
//     (wave2 tanh, others sigm) when writing g4[wave]; tid0 only does the
//     final tanh(c2)+combine. Same ops, same inputs, same combine order ->
//     bitwise identical.
//  2. Merged polls: stage D XR+XI+XR512 in ONE 17-word batched poll (was 2-3
//     serial round-trips); stage H enc+h2b in ONE 3-word poll.
//  3. states1/states2 output writes moved to blocks 64/65 (idle during
//     stages E/H, wgid>=256), taking them fully off block 0's critical path.
//
// All arithmetic and reduction orders byte-identical to rounds 7-10
// (absmax 0.0). dtype: device-side gamma probe -> template<bool BF>.

#define HDIM 128
#define NBLK 128
typedef __hip_bfloat16 bf16;

// ---- tagged scratch: (epoch<<32) | f32 bits ----
__device__ unsigned long long GT[4608];
#define O_H1A 0
#define O_H2A 128
#define O_C1A 256
#define O_C2A 384
#define O_H1B 512
#define O_H2B 640
#define O_C1B 768
#define O_C2B 896
#define O_XR  1024   /* 513 */
#define O_XI  1600   /* 513 */
#define O_Y   2176   /* 1024 */
#define O_ENC 3200   /* 256 */
#define O_EST 3456   /* 256 */

// per-block launch epoch (padded lines)
__device__ unsigned g_epoch[NBLK * 16];

__device__ __forceinline__ unsigned long long gtld(int i) {
    return __hip_atomic_load(&GT[i], __ATOMIC_RELAXED, __HIP_MEMORY_SCOPE_AGENT);
}
__device__ __forceinline__ void postf(int i, float v, unsigned ep) {
    union { float f; unsigned u; } c; c.f = v;
    __hip_atomic_store(&GT[i], ((unsigned long long)ep << 32) | c.u,
                       __ATOMIC_RELAXED, __HIP_MEMORY_SCOPE_AGENT);
}
__device__ __forceinline__ float untag(unsigned long long w) {
    union { unsigned u; float f; } c; c.u = (unsigned)w;
    return c.f;
}
// Batched poll: all N loads in flight per iteration; exits when every tag
// matches this launch's epoch. Detection delay ~= one MALL round-trip.
template <int N>
__device__ __forceinline__ void pollS(int base, int stride, unsigned ep,
                                      float* out) {
    unsigned long long w[N];
    bool ok;
    do {
        ok = true;
#pragma unroll
        for (int j = 0; j < N; ++j)
            w[j] = gtld(base + j * stride);
#pragma unroll
        for (int j = 0; j < N; ++j)
            ok &= ((unsigned)(w[j] >> 32) == ep);
    } while (!ok);
#pragma unroll
    for (int j = 0; j < N; ++j) out[j] = untag(w[j]);
}

__device__ __forceinline__ bool is_bf(const void* probe) {
    return (((const unsigned*)probe)[0] & 0xFFFFu) == 0x3F80u;
}
template <bool BF>
__device__ __forceinline__ float ldin(const void* p, int i) {
    return BF ? __bfloat162float(((const bf16*)p)[i]) : ((const float*)p)[i];
}
template <bool BF>
__device__ __forceinline__ void stout(void* p, int i, float v) {
    if (BF) ((bf16*)p)[i] = __float2bfloat16(v);
    else    ((float*)p)[i] = v;
}
__device__ __forceinline__ float wred(float v) {
#pragma unroll
    for (int m = 32; m; m >>= 1) v += __shfl_xor(v, m);
    return v;
}
__device__ __forceinline__ float sigm(float x) { return 1.f / (1.f + expf(-x)); }

struct Params {
    const void *mag, *phase, *st1, *st2;
    const void *wih10, *whh10, *bih10, *bhh10;
    const void *wih11, *whh11, *bih11, *bhh11;
    const void *d1w, *d1b, *encw, *gamma, *beta;
    const void *wih20, *whh20, *bih20, *bhh20;
    const void *wih21, *whh21, *bih21, *bhh21;
    const void *d2w, *d2b, *decw;
    void *out;
};

struct Smem {
    float tc[1024], ts[1024];   // irfft twiddles
    float xn[256];              // LN output (cross-thread)
    float g4[4];                // per-wave ACTIVATED gate values
    float red[4];
    unsigned ep;                // this launch's epoch
};

template <bool BF>
__device__ void body(const Params& p, Smem& s)
{
    const int tid  = threadIdx.x, lane = tid & 63, wave = tid >> 6;
    const int b    = blockIdx.x;
    const int wgid = b * 4 + wave;           // 0..511 global wave id
    const int row  = wave * HDIM + b;        // LSTM gate row for A/B/F/G

    // epoch: own persistent counter +1 (all blocks in lockstep across
    // serialized launches); broadcast via LDS at stage A's syncthreads.
    if (tid == 0) {
        unsigned e = __hip_atomic_load(&g_epoch[b * 16], __ATOMIC_RELAXED,
                                       __HIP_MEMORY_SCOPE_AGENT) + 1u;
        __hip_atomic_store(&g_epoch[b * 16], e, __ATOMIC_RELAXED,
                           __HIP_MEMORY_SCOPE_AGENT);
        s.ep = e;
    }

    // ======== MINIMAL initial burst: stage-A operands only ========
    float a_w[8], a_x[8], a_wh[2], a_h[2];
#pragma unroll
    for (int i = 0; i < 8; ++i) {
        const int k = lane + 64 * i;
        a_w[i] = ldin<BF>(p.wih10, row * 513 + k);
        a_x[i] = ldin<BF>(p.mag, k);
    }
    float a_w512 = 0.f, a_x512 = 0.f;
    if (lane == 0) {
        a_w512 = ldin<BF>(p.wih10, row * 513 + 512);
        a_x512 = ldin<BF>(p.mag, 512);
    }
#pragma unroll
    for (int i = 0; i < 2; ++i) {
        const int k = lane + 64 * i;
        a_wh[i] = ldin<BF>(p.whh10, row * HDIM + k);
        a_h[i]  = ldin<BF>(p.st1, k);
    }
    float a_bi = ldin<BF>(p.bih10, row), a_bh = ldin<BF>(p.bhh10, row);
    float a_c  = ldin<BF>(p.st1, 256 + b);

    // ================= stage A: lstm1 cell0 =================
    {
        float acc = 0.f;
#pragma unroll
        for (int i = 0; i < 8; ++i) acc += a_w[i] * a_x[i];
        if (lane == 0) acc += a_w512 * a_x512;
#pragma unroll
        for (int i = 0; i < 2; ++i) acc += a_wh[i] * a_h[i];
        acc = wred(acc);
        if (lane == 0) {
            float g = acc + a_bi + a_bh;
            s.g4[wave] = (wave == 2) ? tanhf(g) : sigm(g);   // parallel act
        }
    }
    __syncthreads();                 // g4 ready; s.ep visible to all
    const unsigned ep = s.ep;
    if (tid == 0) {
        float c2 = s.g4[1] * a_c + s.g4[0] * s.g4[2];
        postf(O_H1A + b, s.g4[3] * tanhf(c2), ep);
        postf(O_C1A + b, c2, ep);
    }

    // ======== deferred prefetch of B..I + twiddles (hides under polls) ====
    float b_w[2], b_wh[2], b_h[2];
#pragma unroll
    for (int i = 0; i < 2; ++i) {
        const int k = lane + 64 * i;
        b_w[i]  = ldin<BF>(p.wih11, row * HDIM + k);
        b_wh[i] = ldin<BF>(p.whh11, row * HDIM + k);
        b_h[i]  = ldin<BF>(p.st1, 128 + k);
    }
    float b_bi = ldin<BF>(p.bih11, row), b_bh = ldin<BF>(p.bhh11, row);
    float b_c  = ldin<BF>(p.st1, 384 + b);
    float c_w0[2], c_w1[2] = {0.f, 0.f};
#pragma unroll
    for (int i = 0; i < 2; ++i)
        c_w0[i] = ldin<BF>(p.d1w, wgid * HDIM + lane + 64 * i);
    float c_b0 = ldin<BF>(p.d1b, wgid);
    float c_m0 = ldin<BF>(p.mag, wgid);
    float c_p0 = ldin<BF>(p.phase, wgid);
    float c_b1 = 0.f, c_m1 = 0.f, c_p1 = 0.f;
    if (wgid == 0) {
#pragma unroll
        for (int i = 0; i < 2; ++i)
            c_w1[i] = ldin<BF>(p.d1w, 512 * HDIM + lane + 64 * i);
        c_b1 = ldin<BF>(p.d1b, 512);
        c_m1 = ldin<BF>(p.mag, 512);
        c_p1 = ldin<BF>(p.phase, 512);
    }
    float e_w[16];
    if (wgid < 256) {
#pragma unroll
        for (int i = 0; i < 16; ++i)
            e_w[i] = ldin<BF>(p.encw, wgid * 1024 + lane + 64 * i);
    }
    float f_w[4], f_wh[2], f_h[2];
#pragma unroll
    for (int i = 0; i < 4; ++i)
        f_w[i] = ldin<BF>(p.wih20, row * 256 + lane + 64 * i);
#pragma unroll
    for (int i = 0; i < 2; ++i) {
        const int k = lane + 64 * i;
        f_wh[i] = ldin<BF>(p.whh20, row * HDIM + k);
        f_h[i]  = ldin<BF>(p.st2, k);
    }
    float f_bi = ldin<BF>(p.bih20, row), f_bh = ldin<BF>(p.bhh20, row);
    float f_c  = ldin<BF>(p.st2, 256 + b);
    float f_g  = ldin<BF>(p.gamma, tid), f_be = ldin<BF>(p.beta, tid);
    float g_w[2], g_wh[2], g_h[2];
#pragma unroll
    for (int i = 0; i < 2; ++i) {
        const int k = lane + 64 * i;
        g_w[i]  = ldin<BF>(p.wih21, row * HDIM + k);
        g_wh[i] = ldin<BF>(p.whh21, row * HDIM + k);
        g_h[i]  = ldin<BF>(p.st2, 128 + k);
    }
    float g_bi = ldin<BF>(p.bih21, row), g_bh = ldin<BF>(p.bhh21, row);
    float g_c  = ldin<BF>(p.st2, 384 + b);
    float h_w[2] = {0.f, 0.f}, h_b = 0.f;
    if (wgid < 256) {
#pragma unroll
        for (int i = 0; i < 2; ++i)
            h_w[i] = ldin<BF>(p.d2w, wgid * HDIM + lane + 64 * i);
        h_b = ldin<BF>(p.d2b, wgid);
    }
    float i_w0[4], i_w1[4];
#pragma unroll
    for (int i = 0; i < 4; ++i) {
        i_w0[i] = ldin<BF>(p.decw, wgid * 256 + lane + 64 * i);
        i_w1[i] = ldin<BF>(p.decw, (wgid + 512) * 256 + lane + 64 * i);
    }
    // twiddles: consumed at stage D; stage-B's g4 __syncthreads orders them.
    for (int i = tid; i < 1024; i += 256) {
        float th = (float)i * (6.283185307179586f / 1024.f);
        sincosf(th, &s.ts[i], &s.tc[i]);
    }
    asm volatile("" ::: "memory");   // pin prefetch issue before polls

    // ================= stage B: lstm1 cell1 =================
    {
        float x01[2];
        pollS<2>(O_H1A + lane, 64, ep, x01);
        float acc = b_w[0] * x01[0] + b_w[1] * x01[1];
#pragma unroll
        for (int i = 0; i < 2; ++i) acc += b_wh[i] * b_h[i];
        acc = wred(acc);
        if (lane == 0) {
            float g = acc + b_bi + b_bh;
            s.g4[wave] = (wave == 2) ? tanhf(g) : sigm(g);
        }
    }
    __syncthreads();
    if (tid == 0) {
        float c2 = s.g4[1] * b_c + s.g4[0] * s.g4[2];
        postf(O_H2A + b, s.g4[3] * tanhf(c2), ep);
        postf(O_C2A + b, c2, ep);
    }

    // ========= stage C: mask1 -> spectrum =========
    {
        float h01[2];
        pollS<2>(O_H2A + lane, 64, ep, h01);
        {   // g = wgid
            float acc = c_w0[0] * h01[0] + c_w0[1] * h01[1];
            acc = wred(acc);
            if (lane == 0) {
                float m = sigm(acc + c_b0);
                float em = m * c_m0;
                float sp, cp;
                sincosf(c_p0, &sp, &cp);
                postf(O_XR + wgid, em * cp, ep);
                postf(O_XI + wgid, em * sp, ep);
            }
        }
        if (wgid == 0) {   // g = 512
            float acc = c_w1[0] * h01[0] + c_w1[1] * h01[1];
            acc = wred(acc);
            if (lane == 0) {
                float m = sigm(acc + c_b1);
                float em = m * c_m1;
                float sp, cp;
                sincosf(c_p1, &sp, &cp);
                postf(O_XR + 512, em * cp, ep);
                postf(O_XI + 512, em * sp, ep);
            }
        }
    }

    // ================= stage D: irfft(1024) =================
    {
        // merged 17-word poll: XR[lane+64i], XI[lane+64i], XR[512] -- one
        // detection round-trip instead of three sequential polls.
        float dxr[8], dxi[8], dxr512;
        {
            unsigned long long wr[8], wi[8], w5;
            bool ok;
            do {
                ok = true;
#pragma unroll
                for (int j = 0; j < 8; ++j) {
                    wr[j] = gtld(O_XR + lane + j * 64);
                    wi[j] = gtld(O_XI + lane + j * 64);
                }
                w5 = gtld(O_XR + 512);
#pragma unroll
                for (int j = 0; j < 8; ++j)
                    ok &= ((unsigned)(wr[j] >> 32) == ep) &
                          ((unsigned)(wi[j] >> 32) == ep);
                ok &= ((unsigned)(w5 >> 32) == ep);
            } while (!ok);
#pragma unroll
            for (int j = 0; j < 8; ++j) { dxr[j] = untag(wr[j]); dxi[j] = untag(wi[j]); }
            dxr512 = untag(w5);
        }
#pragma unroll
        for (int r = 0; r < 2; ++r) {
            const int n = wgid + r * 512;
            float acc = 0.f;
            if (lane == 0) {
                acc += dxr[0];
            } else {
                int m = (lane * n) & 1023;
                acc += 2.f * (dxr[0] * s.tc[m] - dxi[0] * s.ts[m]);
            }
#pragma unroll
            for (int i = 1; i < 8; ++i) {
                const int k = lane + 64 * i;
                int m = (k * n) & 1023;
                acc += 2.f * (dxr[i] * s.tc[m] - dxi[i] * s.ts[m]);
            }
            if (lane == 0) acc += (n & 1) ? -dxr512 : dxr512;
            acc = wred(acc);
            if (lane == 0) postf(O_Y + n, acc * (1.f / 1024.f), ep);
        }
    }

    // ================= stage E: encoder =================
    if (wgid < 256) {
        float yv[16];
        pollS<16>(O_Y + lane, 64, ep, yv);
        float acc = 0.f;
#pragma unroll
        for (int i = 0; i < 16; ++i) acc += e_w[i] * yv[i];
        acc = wred(acc);
        if (lane == 0) postf(O_ENC + wgid, acc, ep);
    }
    // block 64 (idle in E): states1 out = [h1a,h2a,c1a,c2a] == GT[0..512),
    // all posted by stage B -- fully off the critical path.
    if (b == 64) {
        float sv[2];
        pollS<2>(tid, 256, ep, sv);
        stout<BF>(p.out, 1024 + tid, sv[0]);
        stout<BF>(p.out, 1024 + tid + 256, sv[1]);
    }

    // ========= stage F: LN(enc) + lstm2 cell0 =========
    {
        float v;
        pollS<1>(O_ENC + tid, 0, ep, &v);
        float sm = wred(v);
        if (lane == 0) s.red[wave] = sm;
        __syncthreads();
        float mean = (s.red[0] + s.red[1] + s.red[2] + s.red[3]) * (1.f / 256.f);
        __syncthreads();
        float d = v - mean;
        float s2 = wred(d * d);
        if (lane == 0) s.red[wave] = s2;
        __syncthreads();
        float var = (s.red[0] + s.red[1] + s.red[2] + s.red[3]) * (1.f / 256.f);
        float rs = rsqrtf(var + 1e-7f);
        s.xn[tid] = d * rs * f_g + f_be;
        __syncthreads();
        float acc = 0.f;
#pragma unroll
        for (int i = 0; i < 4; ++i) acc += f_w[i] * s.xn[lane + 64 * i];
#pragma unroll
        for (int i = 0; i < 2; ++i) acc += f_wh[i] * f_h[i];
        acc = wred(acc);
        if (lane == 0) {
            float g = acc + f_bi + f_bh;
            s.g4[wave] = (wave == 2) ? tanhf(g) : sigm(g);
        }
        __syncthreads();
        if (tid == 0) {
            float c2 = s.g4[1] * f_c + s.g4[0] * s.g4[2];
            postf(O_H1B + b, s.g4[3] * tanhf(c2), ep);
            postf(O_C1B + b, c2, ep);
        }
    }

    // ================= stage G: lstm2 cell1 =================
    {
        float x01[2];
        pollS<2>(O_H1B + lane, 64, ep, x01);
        float acc = g_w[0] * x01[0] + g_w[1] * x01[1];
#pragma unroll
        for (int i = 0; i < 2; ++i) acc += g_wh[i] * g_h[i];
        acc = wred(acc);
        if (lane == 0) {
            float g = acc + g_bi + g_bh;
            s.g4[wave] = (wave == 2) ? tanhf(g) : sigm(g);
        }
    }
    __syncthreads();
    if (tid == 0) {
        float c2 = s.g4[1] * g_c + s.g4[0] * s.g4[2];
        postf(O_H2B + b, s.g4[3] * tanhf(c2), ep);
        postf(O_C2B + b, c2, ep);
    }

    // ========= stage H: mask2 -> est_enc =========
    if (wgid < 256) {
        // merged 3-word poll: enc (long-posted) + 2 h2b words -- one
        // detection round-trip.
        float encv, h0, h1;
        {
            unsigned long long we, w0, w1;
            bool ok;
            do {
                we = gtld(O_ENC + wgid);
                w0 = gtld(O_H2B + lane);
                w1 = gtld(O_H2B + 64 + lane);
                ok = ((unsigned)(we >> 32) == ep) &
                     ((unsigned)(w0 >> 32) == ep) &
                     ((unsigned)(w1 >> 32) == ep);
            } while (!ok);
            encv = untag(we); h0 = untag(w0); h1 = untag(w1);
        }
        float acc = h_w[0] * h0 + h_w[1] * h1;
        acc = wred(acc);
        if (lane == 0) {
            float m = sigm(acc + h_b);
            postf(O_EST + wgid, m * encv, ep);
        }
    }
    // block 65 (idle in E and H): states2 out = [h1b,h2b,c1b,c2b] ==
    // GT[512..1024), all posted by stage G -- off the critical path.
    if (b == 65) {
        float sv[2];
        pollS<2>(512 + tid, 256, ep, sv);
        stout<BF>(p.out, 1536 + tid, sv[0]);
        stout<BF>(p.out, 1536 + tid + 256, sv[1]);
    }

    // ================= stage I: decoder =================
    {
        float e4[4];
        pollS<4>(O_EST + lane, 64, ep, e4);
        {
            float acc = i_w0[0] * e4[0] + i_w0[1] * e4[1] +
                        i_w0[2] * e4[2] + i_w0[3] * e4[3];
            acc = wred(acc);
            if (lane == 0) stout<BF>(p.out, wgid, acc);
        }
        {
            float acc = i_w1[0] * e4[0] + i_w1[1] * e4[1] +
                        i_w1[2] * e4[2] + i_w1[3] * e4[3];
            acc = wred(acc);
            if (lane == 0) stout<BF>(p.out, wgid + 512, acc);
        }
    }
}

__global__ __launch_bounds__(256, 1) void k_fused(Params p)
{
    __shared__ Smem s;
    // Device-side dtype probe (proven): gamma is all-ones.
    if (is_bf(p.gamma)) body<true>(p, s);
    else                body<false>(p, s);
}

extern "C" void kernel_launch(void* const* d_in, const int* in_sizes, int n_in,
                              void* d_out, int out_size, void* d_ws, size_t ws_size,
                              hipStream_t stream)
{
    Params hp;
    hp.mag   = d_in[0];  hp.phase = d_in[1];  hp.st1 = d_in[2];  hp.st2 = d_in[3];
    hp.wih10 = d_in[4];  hp.whh10 = d_in[5];  hp.bih10 = d_in[6];  hp.bhh10 = d_in[7];
    hp.wih11 = d_in[8];  hp.whh11 = d_in[9];  hp.bih11 = d_in[10]; hp.bhh11 = d_in[11];
    hp.d1w   = d_in[12]; hp.d1b   = d_in[13]; hp.encw  = d_in[14];
    hp.gamma = d_in[15]; hp.beta  = d_in[16];
    hp.wih20 = d_in[17]; hp.whh20 = d_in[18]; hp.bih20 = d_in[19]; hp.bhh20 = d_in[20];
    hp.wih21 = d_in[21]; hp.whh21 = d_in[22]; hp.bih21 = d_in[23]; hp.bhh21 = d_in[24];
    hp.d2w   = d_in[25]; hp.d2b   = d_in[26]; hp.decw  = d_in[27];
    hp.out   = d_out;

    hipLaunchKernelGGL(k_fused, dim3(NBLK), dim3(256), 0, stream, hp);
}